// Round 1
// 1018.282 us; speedup vs baseline: 1.5137x; 1.5137x over previous
//
#include <hip/hip_runtime.h>
#include <stdint.h>

#define DIMN 1024
#define TSTEPS 2048
#define BATCH 16
#define MTOT (TSTEPS*BATCH)   // 32768
#define CH (BATCH*DIMN)       // 16384 channels

typedef unsigned short u16;
typedef __attribute__((ext_vector_type(8))) __bf16 bf16x8;
typedef __attribute__((ext_vector_type(4))) float floatx4;

__device__ __forceinline__ float bf2f(u16 u) {
    unsigned v = ((unsigned)u) << 16;
    return __builtin_bit_cast(float, v);
}
__device__ __forceinline__ u16 f2bf(float f) {
    __bf16 b = (__bf16)f;   // RNE convert
    return __builtin_bit_cast(u16, b);
}
__device__ __forceinline__ void gl_lds16(const void* g, void* l) {
    __builtin_amdgcn_global_load_lds(
        (const __attribute__((address_space(1))) void*)g,
        (__attribute__((address_space(3))) void*)l,
        16, 0, 0);
}

#define LOG2E  1.4426950408889634f
#define LOG2E2 2.8853900817779268f

// -------- f32 -> bf16 conversion (x and weights) --------
__global__ void cvt_kernel(const float* __restrict__ src, u16* __restrict__ dst, int n4) {
    int i = blockIdx.x * blockDim.x + threadIdx.x;
    if (i >= n4) return;
    float4 v = ((const float4*)src)[i];
    ushort4 o;
    o.x = f2bf(v.x); o.y = f2bf(v.y); o.z = f2bf(v.z); o.w = f2bf(v.w);
    ((ushort4*)dst)[i] = o;
}

// -------- unified 128x128 MFMA GEMM: C = A(bf16) * W(bf16)^T, epilogue by mode --------
__global__ __launch_bounds__(256) void gemm_bt(
    const u16* __restrict__ A, const u16* __restrict__ W,
    const float* __restrict__ bias,
    u16* __restrict__ outB, float* __restrict__ outF,
    const u16* __restrict__ cmp, int mode)
{
    __shared__ alignas(16) u16 a_sh[128 * 32];
    __shared__ alignas(16) u16 b_sh[128 * 32];
    const int tid  = threadIdx.x;
    const int lane = tid & 63;
    const int wave = tid >> 6;
    const int wm = wave & 1, wn = wave >> 1;
    const int m0 = blockIdx.x * 128, n0 = blockIdx.y * 128;
    const int row = lane & 15, quad = lane >> 4;

    const u16* Ag0 = A + (size_t)(m0 + (tid >> 2)) * DIMN + (tid & 3) * 8;
    const u16* Ag1 = Ag0 + (size_t)64 * DIMN;
    const u16* Wg0 = W + (size_t)(n0 + (tid >> 2)) * DIMN + (tid & 3) * 8;
    const u16* Wg1 = Wg0 + (size_t)64 * DIMN;
    u16* a_d0 = a_sh + tid * 8; u16* a_d1 = a_sh + 2048 + tid * 8;
    u16* b_d0 = b_sh + tid * 8; u16* b_d1 = b_sh + 2048 + tid * 8;

    floatx4 acc[4][4];
    #pragma unroll
    for (int i = 0; i < 4; i++)
        #pragma unroll
        for (int j = 0; j < 4; j++) acc[i][j] = (floatx4)(0.0f);

    int aoff[4], boff[4];
    #pragma unroll
    for (int i = 0; i < 4; i++) aoff[i] = (wm * 64 + i * 16 + row) * 32 + quad * 8;
    #pragma unroll
    for (int j = 0; j < 4; j++) boff[j] = (wn * 64 + j * 16 + row) * 32 + quad * 8;

    for (int kt = 0; kt < DIMN; kt += 32) {
        __syncthreads();
        gl_lds16(Ag0 + kt, a_d0);
        gl_lds16(Ag1 + kt, a_d1);
        gl_lds16(Wg0 + kt, b_d0);
        gl_lds16(Wg1 + kt, b_d1);
        __syncthreads();
        bf16x8 av[4], bv[4];
        #pragma unroll
        for (int i = 0; i < 4; i++) av[i] = *(const bf16x8*)(a_sh + aoff[i]);
        #pragma unroll
        for (int j = 0; j < 4; j++) bv[j] = *(const bf16x8*)(b_sh + boff[j]);
        #pragma unroll
        for (int i = 0; i < 4; i++)
            #pragma unroll
            for (int j = 0; j < 4; j++)
                acc[i][j] = __builtin_amdgcn_mfma_f32_16x16x32_bf16(av[i], bv[j], acc[i][j], 0, 0, 0);
    }

    // C/D mapping: col = lane&15, row = quad*4 + reg
    const int mb = m0 + wm * 64 + quad * 4;
    const int nb = n0 + wn * 64 + row;
    if (mode == 2) {
        #pragma unroll
        for (int i = 0; i < 4; i++)
            #pragma unroll
            for (int j = 0; j < 4; j++)
                #pragma unroll
                for (int r = 0; r < 4; r++) {
                    size_t idx = (size_t)(mb + i * 16 + r) * DIMN + (nb + j * 16);
                    float z = acc[i][j][r];
                    float sil = z * __builtin_amdgcn_rcpf(1.f + __builtin_amdgcn_exp2f(-z * LOG2E));
                    outF[idx] = bf2f(cmp[idx]) * sil;
                }
    } else if (mode == 0) {
        #pragma unroll
        for (int i = 0; i < 4; i++)
            #pragma unroll
            for (int j = 0; j < 4; j++)
                #pragma unroll
                for (int r = 0; r < 4; r++) {
                    int n = nb + j * 16;
                    float v = acc[i][j][r] + bias[n];
                    v = __builtin_amdgcn_rcpf(1.f + __builtin_amdgcn_exp2f(-v * LOG2E));
                    outB[(size_t)(mb + i * 16 + r) * DIMN + n] = f2bf(v);
                }
    } else {
        #pragma unroll
        for (int i = 0; i < 4; i++)
            #pragma unroll
            for (int j = 0; j < 4; j++)
                #pragma unroll
                for (int r = 0; r < 4; r++) {
                    int n = nb + j * 16;
                    float v = acc[i][j][r] + bias[n];
                    outB[(size_t)(mb + i * 16 + r) * DIMN + n] = f2bf(v);
                }
    }
}

// -------- diagonal scan, LDS double-buffered staging, fused softmax/bf16 epilogue --------
// One wave (64 threads) per block, one channel per lane, 256 blocks cover CH=16384.
// Chunked staging: 64 steps x 64 ch per buffer per array; global_load_lds 16B/lane
// gives [step][ch] LDS layout natively (lane l -> step l>>3, ch (l&7)*8).
// Counted vmcnt(16) keeps next chunk's 16 staging loads in flight across compute.
#define CS 64
#define SB 8
__global__ __launch_bounds__(64) void scan_kernel(
    const u16* __restrict__ dB, const u16* __restrict__ cB,
    const float* __restrict__ h0, const float* __restrict__ r_h,
    float* __restrict__ hAll, u16* __restrict__ hB, u16* __restrict__ cmpB)
{
    __shared__ alignas(16) u16 d_sh[2][CS * 64];
    __shared__ alignas(16) u16 c_sh[2][CS * 64];
    const int tid = threadIdx.x;
    const int c0 = blockIdx.x * 64;
    const int c  = c0 + tid;
    const int d  = c & (DIMN - 1);

    float h = h0[c];
    const float r2 = r_h[d] * LOG2E2;   // fold 2*log2(e) into the per-channel constant
    hAll[c] = h;                        // h_all[0] = h0

    // Per-lane global source for 16B staging loads: step group row = tid>>3, col = (tid&7)*8
    const u16* dG = dB + (size_t)(tid >> 3) * CH + c0 + (tid & 7) * 8;
    const u16* cG = cB + (size_t)(tid >> 3) * CH + c0 + (tid & 7) * 8;

    // Prologue: stage chunk 0 into buffer 0 (16 loads)
    #pragma unroll
    for (int s = 0; s < 8; s++) {
        gl_lds16(dG + (size_t)(s * 8) * CH, (void*)&d_sh[0][s * 512]);
        gl_lds16(cG + (size_t)(s * 8) * CH, (void*)&c_sh[0][s * 512]);
    }

    float* hOut  = hAll + CH + c;   // h_{t+1} stream (f32, required output)
    u16* hbOut   = hB + c;          // bf16(h_{t+1}) for the output GEMM
    u16* cmpOut  = cmpB + c;        // softmax(compete) bf16

    for (int t0 = 0; t0 < TSTEPS; t0 += CS) {
        const int buf = (t0 / CS) & 1;
        if (t0 + CS < TSTEPS) {
            // issue next chunk's 16 staging loads, then wait only for the CURRENT
            // chunk (everything older than the 16 just issued)
            #pragma unroll
            for (int s = 0; s < 8; s++) {
                gl_lds16(dG + (size_t)(t0 + CS + s * 8) * CH, (void*)&d_sh[buf ^ 1][s * 512]);
                gl_lds16(cG + (size_t)(t0 + CS + s * 8) * CH, (void*)&c_sh[buf ^ 1][s * 512]);
            }
            asm volatile("s_waitcnt vmcnt(16)" ::: "memory");
        } else {
            asm volatile("s_waitcnt vmcnt(0)" ::: "memory");
        }
        __builtin_amdgcn_sched_barrier(0);

        const u16* dS = d_sh[buf];
        const u16* cS = c_sh[buf];

        #pragma unroll
        for (int sb = 0; sb < CS / SB; sb++) {
            float hv[SB];
            // --- recurrence: the only serial chain (fma -> exp2 -> rcp -> fma -> fma) ---
            #pragma unroll
            for (int i = 0; i < SB; i++) {
                const int s = sb * SB + i;
                float dlt  = bf2f(dS[s * 64 + tid]);
                float cin2 = bf2f(cS[s * 64 + tid]) * LOG2E2;   // off-chain
                float e    = __builtin_amdgcn_exp2f(fmaf(r2, h, cin2));
                float cand = fmaf(-2.f, __builtin_amdgcn_rcpf(e + 1.f), 1.f);  // tanh
                h = fmaf(dlt, cand - h, h);                     // (1-d)h + d*cand
                hv[i] = h;
                hOut[(size_t)(t0 + s) * CH] = h;
            }
            // --- fused epilogue (off the recurrence path): group softmax + bf16 casts ---
            // |h| < 1 by induction (h0=0, convex comb. with tanh) => no max subtraction.
            #pragma unroll
            for (int i = 0; i < SB; i++) {
                const int s = sb * SB + i;
                float ex = __builtin_amdgcn_exp2f(hv[i] * LOG2E);
                float sum = ex;
                #pragma unroll
                for (int m = 16; m > 0; m >>= 1) sum += __shfl_xor(sum, m);  // 32-lane group
                float cmpv = ex * __builtin_amdgcn_rcpf(sum);
                cmpOut[(size_t)(t0 + s) * CH] = f2bf(cmpv);
                hbOut[(size_t)(t0 + s) * CH]  = f2bf(hv[i]);
            }
        }
    }
}

extern "C" void kernel_launch(void* const* d_in, const int* in_sizes, int n_in,
                              void* d_out, int out_size, void* d_ws, size_t ws_size,
                              hipStream_t stream) {
    const float* x   = (const float*)d_in[0];
    const float* h0  = (const float*)d_in[1];
    const float* W_x = (const float*)d_in[2];
    const float* r_h = (const float*)d_in[3];
    const float* b   = (const float*)d_in[4];
    const float* W_d = (const float*)d_in[5];
    const float* b_d = (const float*)d_in[6];
    const float* W_o = (const float*)d_in[7];
    float* out = (float*)d_out;

    char* ws = (char*)d_ws;
    u16* xb   = (u16*)(ws);
    u16* wdB  = (u16*)(ws + 67108864);
    u16* wxB  = (u16*)(ws + 69206016);
    u16* woB  = (u16*)(ws + 71303168);
    u16* dBuf = (u16*)(ws + 73400320);
    u16* cBuf = (u16*)(ws + 140509184);
    u16* cmpB = (u16*)(ws + 207618048);
    u16* hB   = xb;   // xb dead after the two pre-GEMMs

    cvt_kernel<<<dim3(33554432 / 4 / 256), 256, 0, stream>>>(x, xb, 33554432 / 4);
    cvt_kernel<<<dim3(1048576 / 4 / 256), 256, 0, stream>>>(W_d, wdB, 1048576 / 4);
    cvt_kernel<<<dim3(1048576 / 4 / 256), 256, 0, stream>>>(W_x, wxB, 1048576 / 4);
    cvt_kernel<<<dim3(1048576 / 4 / 256), 256, 0, stream>>>(W_o, woB, 1048576 / 4);

    dim3 g(MTOT / 128, DIMN / 128);   // 256 x 8
    gemm_bt<<<g, 256, 0, stream>>>(xb, wdB, b_d, dBuf, nullptr, nullptr, 0);
    gemm_bt<<<g, 256, 0, stream>>>(xb, wxB, b,   cBuf, nullptr, nullptr, 1);
    // fused: scan + group-softmax + bf16 casts (post_kernel eliminated)
    scan_kernel<<<256, 64, 0, stream>>>(dBuf, cBuf, h0, r_h, out, hB, cmpB);
    gemm_bt<<<g, 256, 0, stream>>>(hB, woB, nullptr, nullptr, out + 33570816, cmpB, 2);
}

// Round 2
// 865.489 us; speedup vs baseline: 1.7809x; 1.1765x over previous
//
#include <hip/hip_runtime.h>
#include <stdint.h>

#define DIMN 1024
#define TSTEPS 2048
#define BATCH 16
#define MTOT (TSTEPS*BATCH)   // 32768
#define CH (BATCH*DIMN)       // 16384 channels

typedef unsigned short u16;
typedef __attribute__((ext_vector_type(8))) __bf16 bf16x8;
typedef __attribute__((ext_vector_type(4))) float floatx4;

__device__ __forceinline__ float bf2f(u16 u) {
    unsigned v = ((unsigned)u) << 16;
    return __builtin_bit_cast(float, v);
}
__device__ __forceinline__ u16 f2bf(float f) {
    __bf16 b = (__bf16)f;   // RNE convert
    return __builtin_bit_cast(u16, b);
}
__device__ __forceinline__ void gl_lds16(const void* g, void* l) {
    __builtin_amdgcn_global_load_lds(
        (const __attribute__((address_space(1))) void*)g,
        (__attribute__((address_space(3))) void*)l,
        16, 0, 0);
}

#define LOG2E  1.4426950408889634f
#define LOG2E2 2.8853900817779268f

// -------- f32 -> bf16 conversion (x and weights) --------
__global__ void cvt_kernel(const float* __restrict__ src, u16* __restrict__ dst, int n4) {
    int i = blockIdx.x * blockDim.x + threadIdx.x;
    if (i >= n4) return;
    float4 v = ((const float4*)src)[i];
    ushort4 o;
    o.x = f2bf(v.x); o.y = f2bf(v.y); o.z = f2bf(v.z); o.w = f2bf(v.w);
    ((ushort4*)dst)[i] = o;
}

// -------- unified 128x128 MFMA GEMM: C = A(bf16) * W(bf16)^T, epilogue by mode --------
__global__ __launch_bounds__(256) void gemm_bt(
    const u16* __restrict__ A, const u16* __restrict__ W,
    const float* __restrict__ bias,
    u16* __restrict__ outB, float* __restrict__ outF,
    const u16* __restrict__ cmp, int mode)
{
    __shared__ alignas(16) u16 a_sh[128 * 32];
    __shared__ alignas(16) u16 b_sh[128 * 32];
    const int tid  = threadIdx.x;
    const int lane = tid & 63;
    const int wave = tid >> 6;
    const int wm = wave & 1, wn = wave >> 1;
    const int m0 = blockIdx.x * 128, n0 = blockIdx.y * 128;
    const int row = lane & 15, quad = lane >> 4;

    const u16* Ag0 = A + (size_t)(m0 + (tid >> 2)) * DIMN + (tid & 3) * 8;
    const u16* Ag1 = Ag0 + (size_t)64 * DIMN;
    const u16* Wg0 = W + (size_t)(n0 + (tid >> 2)) * DIMN + (tid & 3) * 8;
    const u16* Wg1 = Wg0 + (size_t)64 * DIMN;
    u16* a_d0 = a_sh + tid * 8; u16* a_d1 = a_sh + 2048 + tid * 8;
    u16* b_d0 = b_sh + tid * 8; u16* b_d1 = b_sh + 2048 + tid * 8;

    floatx4 acc[4][4];
    #pragma unroll
    for (int i = 0; i < 4; i++)
        #pragma unroll
        for (int j = 0; j < 4; j++) acc[i][j] = (floatx4)(0.0f);

    int aoff[4], boff[4];
    #pragma unroll
    for (int i = 0; i < 4; i++) aoff[i] = (wm * 64 + i * 16 + row) * 32 + quad * 8;
    #pragma unroll
    for (int j = 0; j < 4; j++) boff[j] = (wn * 64 + j * 16 + row) * 32 + quad * 8;

    for (int kt = 0; kt < DIMN; kt += 32) {
        __syncthreads();
        gl_lds16(Ag0 + kt, a_d0);
        gl_lds16(Ag1 + kt, a_d1);
        gl_lds16(Wg0 + kt, b_d0);
        gl_lds16(Wg1 + kt, b_d1);
        __syncthreads();
        bf16x8 av[4], bv[4];
        #pragma unroll
        for (int i = 0; i < 4; i++) av[i] = *(const bf16x8*)(a_sh + aoff[i]);
        #pragma unroll
        for (int j = 0; j < 4; j++) bv[j] = *(const bf16x8*)(b_sh + boff[j]);
        #pragma unroll
        for (int i = 0; i < 4; i++)
            #pragma unroll
            for (int j = 0; j < 4; j++)
                acc[i][j] = __builtin_amdgcn_mfma_f32_16x16x32_bf16(av[i], bv[j], acc[i][j], 0, 0, 0);
    }

    // C/D mapping: col = lane&15, row = quad*4 + reg
    const int mb = m0 + wm * 64 + quad * 4;
    const int nb = n0 + wn * 64 + row;
    if (mode == 2) {
        #pragma unroll
        for (int i = 0; i < 4; i++)
            #pragma unroll
            for (int j = 0; j < 4; j++)
                #pragma unroll
                for (int r = 0; r < 4; r++) {
                    size_t idx = (size_t)(mb + i * 16 + r) * DIMN + (nb + j * 16);
                    float z = acc[i][j][r];
                    float sil = z * __builtin_amdgcn_rcpf(1.f + __builtin_amdgcn_exp2f(-z * LOG2E));
                    outF[idx] = bf2f(cmp[idx]) * sil;
                }
    } else if (mode == 0) {
        #pragma unroll
        for (int i = 0; i < 4; i++)
            #pragma unroll
            for (int j = 0; j < 4; j++)
                #pragma unroll
                for (int r = 0; r < 4; r++) {
                    int n = nb + j * 16;
                    float v = acc[i][j][r] + bias[n];
                    v = __builtin_amdgcn_rcpf(1.f + __builtin_amdgcn_exp2f(-v * LOG2E));
                    outB[(size_t)(mb + i * 16 + r) * DIMN + n] = f2bf(v);
                }
    } else {
        #pragma unroll
        for (int i = 0; i < 4; i++)
            #pragma unroll
            for (int j = 0; j < 4; j++)
                #pragma unroll
                for (int r = 0; r < 4; r++) {
                    int n = nb + j * 16;
                    float v = acc[i][j][r] + bias[n];
                    outB[(size_t)(mb + i * 16 + r) * DIMN + n] = f2bf(v);
                }
    }
}

// -------- diagonal scan: recurrence ONLY (+ f32 and bf16 h stores in chain shadow) --------
// One wave per block, one channel per lane, 256 blocks = 1 wave/CU.
// Serial chain per step (re-associated): fma -> exp2 -> add -> rcp -> fma (~28 cy);
// `base` and `-2*dlt` computed in parallel with the exp path.
// Softmax epilogue moved OUT (it was 5 dependent ds_swizzles/step = ~150 cy of
// cross-lane latency that 1 wave/CU cannot hide) -> post_kernel.
#define CS 64
#define SB 8
__global__ __launch_bounds__(64) void scan_kernel(
    const u16* __restrict__ dB, const u16* __restrict__ cB,
    const float* __restrict__ h0, const float* __restrict__ r_h,
    float* __restrict__ hAll, u16* __restrict__ hB)
{
    __shared__ alignas(16) u16 d_sh[2][CS * 64];
    __shared__ alignas(16) u16 c_sh[2][CS * 64];
    const int tid = threadIdx.x;
    const int c0 = blockIdx.x * 64;
    const int c  = c0 + tid;
    const int d  = c & (DIMN - 1);

    float h = h0[c];
    const float r2 = r_h[d] * LOG2E2;   // fold 2*log2(e) into the per-channel constant
    hAll[c] = h;                        // h_all[0] = h0

    // Per-lane global source for 16B staging loads: step group row = tid>>3, col = (tid&7)*8
    const u16* dG = dB + (size_t)(tid >> 3) * CH + c0 + (tid & 7) * 8;
    const u16* cG = cB + (size_t)(tid >> 3) * CH + c0 + (tid & 7) * 8;

    // Prologue: stage chunk 0 into buffer 0 (16 loads)
    #pragma unroll
    for (int s = 0; s < 8; s++) {
        gl_lds16(dG + (size_t)(s * 8) * CH, (void*)&d_sh[0][s * 512]);
        gl_lds16(cG + (size_t)(s * 8) * CH, (void*)&c_sh[0][s * 512]);
    }

    float* hOut = hAll + CH + c;   // h_{t+1} stream (f32, required output)
    u16* hbOut  = hB + c;          // bf16(h_{t+1}) for the output GEMM

    for (int t0 = 0; t0 < TSTEPS; t0 += CS) {
        const int buf = (t0 / CS) & 1;
        if (t0 + CS < TSTEPS) {
            // issue next chunk's 16 staging loads, then wait only for the CURRENT
            // chunk (everything older than the 16 just issued)
            #pragma unroll
            for (int s = 0; s < 8; s++) {
                gl_lds16(dG + (size_t)(t0 + CS + s * 8) * CH, (void*)&d_sh[buf ^ 1][s * 512]);
                gl_lds16(cG + (size_t)(t0 + CS + s * 8) * CH, (void*)&c_sh[buf ^ 1][s * 512]);
            }
            asm volatile("s_waitcnt vmcnt(16)" ::: "memory");
        } else {
            asm volatile("s_waitcnt vmcnt(0)" ::: "memory");
        }
        __builtin_amdgcn_sched_barrier(0);

        const u16* dS = d_sh[buf];
        const u16* cS = c_sh[buf];

        #pragma unroll
        for (int sb = 0; sb < CS / SB; sb++) {
            #pragma unroll
            for (int i = 0; i < SB; i++) {
                const int s = sb * SB + i;
                float dlt  = bf2f(dS[s * 64 + tid]);
                float cin2 = bf2f(cS[s * 64 + tid]) * LOG2E2;   // off-chain
                // critical chain: fma -> exp2 -> add -> rcp -> fma
                float e    = __builtin_amdgcn_exp2f(fmaf(r2, h, cin2));
                float q    = __builtin_amdgcn_rcpf(e + 1.f);
                // off-chain (parallel with exp2/rcp): base = h - dlt*h + dlt, m2d = -2*dlt
                float base = fmaf(-dlt, h, h) + dlt;
                float m2d  = -2.f * dlt;
                h = fmaf(m2d, q, base);   // == (1-dlt)*h + dlt*tanh(...)
                hOut[(size_t)(t0 + s) * CH] = h;
                hbOut[(size_t)(t0 + s) * CH] = f2bf(h);
            }
        }
    }
}

// -------- parallel group-softmax (post-scan, BW-bound) --------
// one thread = 4 channels (float4); 8 threads = one 32-wide softmax group.
// |h| < 1 by induction (h0=0, convex comb. with tanh) => no max subtraction needed.
__global__ __launch_bounds__(256) void post_kernel(
    const float* __restrict__ hAll, u16* __restrict__ cmp)
{
    const int gid = blockIdx.x * 256 + threadIdx.x;     // over T*CH/4
    float4 hv = ((const float4*)(hAll + CH))[gid];

    float ex = __builtin_amdgcn_exp2f(hv.x * LOG2E);
    float ey = __builtin_amdgcn_exp2f(hv.y * LOG2E);
    float ez = __builtin_amdgcn_exp2f(hv.z * LOG2E);
    float ew = __builtin_amdgcn_exp2f(hv.w * LOG2E);
    float sum = (ex + ey) + (ez + ew);
    #pragma unroll
    for (int s = 4; s > 0; s >>= 1) sum += __shfl_xor(sum, s);  // 8-thread group = 32 ch
    float inv = __builtin_amdgcn_rcpf(sum);

    ushort4 co;
    co.x = f2bf(ex * inv); co.y = f2bf(ey * inv);
    co.z = f2bf(ez * inv); co.w = f2bf(ew * inv);
    ((ushort4*)cmp)[gid] = co;
}

extern "C" void kernel_launch(void* const* d_in, const int* in_sizes, int n_in,
                              void* d_out, int out_size, void* d_ws, size_t ws_size,
                              hipStream_t stream) {
    const float* x   = (const float*)d_in[0];
    const float* h0  = (const float*)d_in[1];
    const float* W_x = (const float*)d_in[2];
    const float* r_h = (const float*)d_in[3];
    const float* b   = (const float*)d_in[4];
    const float* W_d = (const float*)d_in[5];
    const float* b_d = (const float*)d_in[6];
    const float* W_o = (const float*)d_in[7];
    float* out = (float*)d_out;

    char* ws = (char*)d_ws;
    u16* xb   = (u16*)(ws);
    u16* wdB  = (u16*)(ws + 67108864);
    u16* wxB  = (u16*)(ws + 69206016);
    u16* woB  = (u16*)(ws + 71303168);
    u16* dBuf = (u16*)(ws + 73400320);
    u16* cBuf = (u16*)(ws + 140509184);
    u16* cmpB = (u16*)(ws + 207618048);
    u16* hB   = xb;   // xb dead after the two pre-GEMMs

    cvt_kernel<<<dim3(33554432 / 4 / 256), 256, 0, stream>>>(x, xb, 33554432 / 4);
    cvt_kernel<<<dim3(1048576 / 4 / 256), 256, 0, stream>>>(W_d, wdB, 1048576 / 4);
    cvt_kernel<<<dim3(1048576 / 4 / 256), 256, 0, stream>>>(W_x, wxB, 1048576 / 4);
    cvt_kernel<<<dim3(1048576 / 4 / 256), 256, 0, stream>>>(W_o, woB, 1048576 / 4);

    dim3 g(MTOT / 128, DIMN / 128);   // 256 x 8
    gemm_bt<<<g, 256, 0, stream>>>(xb, wdB, b_d, dBuf, nullptr, nullptr, 0);
    gemm_bt<<<g, 256, 0, stream>>>(xb, wxB, b,   cBuf, nullptr, nullptr, 1);
    scan_kernel<<<256, 64, 0, stream>>>(dBuf, cBuf, h0, r_h, out, hB);
    post_kernel<<<dim3(TSTEPS * CH / 4 / 256), 256, 0, stream>>>(out, cmpB);
    gemm_bt<<<g, 256, 0, stream>>>(hB, woB, nullptr, nullptr, out + 33570816, cmpB, 2);
}